// Round 6
// baseline (691.408 us; speedup 1.0000x reference)
//
#include <hip/hip_runtime.h>

// Fused GQA attention layer for MI355X (gfx950).
// B=2 S=2048 E=4096 HQ=32 HKV=8 D=128 WINDOW=1024 SOFT_CAP=50 Q_PRE_ATTN=128
//
// R10: attn_fwd rebuilt on 32x32x16 MFMA to HALVE per-wave LDS reads
//   (K/V each read by 2 waves instead of 4; Q in regs; P = shared 64x64
//   swizzled LDS tile + 1 extra barrier). LDS 40KB -> 4 blk/CU.
//   Theory: attn is LDS-pipe-bound (~144KB LDS reads per block-tile);
//   R7/R8 staging dbufs were neutral => not stage-latency-bound.
//   + transpose kernels: stores now 64B-contiguous (R9 had 8B@8KB-stride).
//   gemm256 / qkv_post / cast unchanged (gemm measured-stable 227us).
//
// Workspace layout (160 MiB, regions reused over time):
//   [0,        33.5M)  xb        -> later vtb
//   [33.5M,    83.9M)  WqkvT     -> later qb|kb
//   [83.9M,   117.4M)  WoT       (persistent)
//   [117.4M,  167.8M)  qkv_raw   -> later attn

typedef unsigned short u16;
typedef unsigned int   u32;
typedef __bf16 bf16x8 __attribute__((ext_vector_type(8)));
typedef float  f32x4  __attribute__((ext_vector_type(4)));
typedef float  f32x16 __attribute__((ext_vector_type(16)));

typedef __attribute__((address_space(1))) void* gas_ptr;
typedef __attribute__((address_space(3))) void* las_ptr;

__device__ __forceinline__ void load_lds16(const void* g, void* l) {
  __builtin_amdgcn_global_load_lds((gas_ptr)g, (las_ptr)l, 16, 0, 0);
}

__device__ __forceinline__ u16 f2bf(float f) {
  u32 u = __builtin_bit_cast(u32, f);
  u += 0x7fffu + ((u >> 16) & 1u);   // RNE
  return (u16)(u >> 16);
}
__device__ __forceinline__ float bf2f(u16 h) {
  u32 u = ((u32)h) << 16;
  return __builtin_bit_cast(float, u);
}
// truncate-pack two fp32 -> bf16 pair (low = a, high = b)
__device__ __forceinline__ u32 pack_trunc(float a, float b) {
  return (__builtin_bit_cast(u32, a) >> 16) | (__builtin_bit_cast(u32, b) & 0xffff0000u);
}

// ---------------------------------------------------------------- cast x
__global__ __launch_bounds__(256) void cast_f32_bf16(const float* __restrict__ src,
                                                     u16* __restrict__ dst) {
  size_t i = ((size_t)blockIdx.x * 256 + threadIdx.x) * 8;
  float4 a = *(const float4*)(src + i);
  float4 b = *(const float4*)(src + i + 4);
  uint4 o;
  o.x = (u32)f2bf(a.x) | ((u32)f2bf(a.y) << 16);
  o.y = (u32)f2bf(a.z) | ((u32)f2bf(a.w) << 16);
  o.z = (u32)f2bf(b.x) | ((u32)f2bf(b.y) << 16);
  o.w = (u32)f2bf(b.z) | ((u32)f2bf(b.w) << 16);
  *(uint4*)(dst + i) = o;
}

// ------------------------------------------------- transpose-cast fp32->bf16
// dst[C][R] = cast(src[R][C]); writes: 8 lanes x uint2 = 64B contiguous/row.
__global__ __launch_bounds__(256) void transpose_cast_f32_bf16(
    const float* __restrict__ src, u16* __restrict__ dst, int R, int C) {
  __shared__ float tile[32][33];
  const int tx = threadIdx.x & 31, ty = threadIdx.x >> 5;
  const int r0 = blockIdx.y * 32, c0 = blockIdx.x * 32;
#pragma unroll
  for (int i = 0; i < 4; ++i)
    tile[ty + i * 8][tx] = src[(size_t)(r0 + ty + i * 8) * C + (c0 + tx)];
  __syncthreads();
  const int cc = threadIdx.x >> 3;       // output row (src col) 0..31
  const int rg = threadIdx.x & 7;        // 4-elem group along r
  uint2 ov;
  ov.x = (u32)f2bf(tile[rg * 4 + 0][cc]) | ((u32)f2bf(tile[rg * 4 + 1][cc]) << 16);
  ov.y = (u32)f2bf(tile[rg * 4 + 2][cc]) | ((u32)f2bf(tile[rg * 4 + 3][cc]) << 16);
  *(uint2*)&dst[(size_t)(c0 + cc) * R + (r0 + rg * 4)] = ov;
}

// ------------------------------------------------- V plane transpose from qkvr
// vtb[plane][d][pos] = qkvr[(b,pos)][(40+h8)*128 + d]; plane = b*8+h8.
__global__ __launch_bounds__(256) void transpose_v(const u16* __restrict__ qkvr,
                                                   u16* __restrict__ vtb) {
  __shared__ u16 tile[32][34];
  const int plane = blockIdx.z;
  const int b = plane >> 3, h8 = plane & 7;
  const u16* s = qkvr + (size_t)(b * 2048) * 6144 + (40 + h8) * 128;
  u16* d = vtb + (size_t)plane * 2048 * 128;
  const int tx = threadIdx.x & 31, ty = threadIdx.x >> 5;
  const int r0 = blockIdx.x * 32, c0 = blockIdx.y * 32;   // r=pos, c=d
#pragma unroll
  for (int i = 0; i < 4; ++i)
    tile[ty + i * 8][tx] = s[(size_t)(r0 + ty + i * 8) * 6144 + (c0 + tx)];
  __syncthreads();
  const int cc = threadIdx.x >> 3;
  const int rg = threadIdx.x & 7;
  uint2 ov;
  ov.x = (u32)tile[rg * 4 + 0][cc] | ((u32)tile[rg * 4 + 1][cc] << 16);
  ov.y = (u32)tile[rg * 4 + 2][cc] | ((u32)tile[rg * 4 + 3][cc] << 16);
  *(uint2*)&d[(size_t)(c0 + cc) * 2048 + (r0 + rg * 4)] = ov;
}

// ---------------------------------------------------------------- GEMM 256^2 8-phase
// C[M][N] = A[M][K] @ Bt[N][K]^T. Requires: M%256==0, N%256==0, K%128==0,
// grid = (M/256)*(N/256) with grid%8==0.  (unchanged, measured-stable 227us)

template <int MB>
__device__ __forceinline__ void mm16(f32x4 (&acc)[8][4], const bf16x8 (&af)[4],
                                     const bf16x8 (&bf)[4]) {
#pragma unroll
  for (int ii = 0; ii < 4; ++ii)
#pragma unroll
    for (int nf = 0; nf < 4; ++nf)
      acc[MB + ii][nf] =
          __builtin_amdgcn_mfma_f32_16x16x32_bf16(af[ii], bf[nf], acc[MB + ii][nf], 0, 0, 0);
}

template <int OUT_BF16>
__global__ __launch_bounds__(512, 2) void gemm256(const u16* __restrict__ A,
                                                  const u16* __restrict__ Bt,
                                                  void* __restrict__ Cout,
                                                  int N, int K, int ntx) {
  __shared__ __align__(16) u16 lds[65536];   // 128 KiB
  const int t = threadIdx.x, lane = t & 63, w = t >> 6;
  const int c = lane & 15, q = lane >> 4;
  const int wm = w >> 2, wn = w & 3;

  const int cpx = (int)gridDim.x >> 3;
  const int swz = ((int)blockIdx.x & 7) * cpx + ((int)blockIdx.x >> 3);
  const int bx = swz % ntx, by = swz / ntx;
  const int m0 = by << 8, n0 = bx << 8;

  u32 aoff[2][2], boff[2][2];
#pragma unroll
  for (int h = 0; h < 2; ++h)
#pragma unroll
    for (int j = 0; j < 2; ++j) {
      const int rowS = w * 16 + j * 8 + (lane >> 3);
      const int colE = ((lane & 7) ^ (rowS & 7)) * 8;
      aoff[h][j] = (u32)(m0 + h * 128 + rowS) * (u32)K + (u32)colE;
      boff[h][j] = (u32)(n0 + h * 128 + rowS) * (u32)K + (u32)colE;
    }
  const u32 stW = (u32)w * 1024u;

  const u32 sl0 = (u32)((q ^ (c & 7)) * 8);
  const u32 aR = (u32)(wm * 8192 + c * 64) + sl0;
  const u32 bR = (u32)(16384 + (wn >> 1) * 8192 + (wn & 1) * 4096 + c * 64) + sl0;

  f32x4 acc[8][4];
#pragma unroll
  for (int i2 = 0; i2 < 8; ++i2)
#pragma unroll
    for (int j2 = 0; j2 < 4; ++j2) acc[i2][j2] = (f32x4){0.f, 0.f, 0.f, 0.f};

  const int nt = K >> 6;

#define STG_A(bb, hh, kt)                                                \
  do {                                                                   \
    u16* d_ = &lds[(bb) * 32768u + (hh) * 8192u + stW];                  \
    load_lds16(A + (aoff[hh][0] + (u32)(kt) * 64u), d_);                 \
    load_lds16(A + (aoff[hh][1] + (u32)(kt) * 64u), d_ + 512);           \
  } while (0)
#define STG_B(bb, hh, kt)                                                \
  do {                                                                   \
    u16* d_ = &lds[(bb) * 32768u + 16384u + (hh) * 8192u + stW];         \
    load_lds16(Bt + (boff[hh][0] + (u32)(kt) * 64u), d_);                \
    load_lds16(Bt + (boff[hh][1] + (u32)(kt) * 64u), d_ + 512);          \
  } while (0)
#define RD4(dst, base)                                                   \
  do {                                                                   \
    const u16* p_ = &lds[(base)];                                        \
    dst[0] = *(const bf16x8*)(p_);                                       \
    dst[1] = *(const bf16x8*)(p_ + 1024);                                \
    dst[2] = *(const bf16x8*)(p_ + 2048);                                \
    dst[3] = *(const bf16x8*)(p_ + 3072);                                \
  } while (0)
#define BAR __builtin_amdgcn_s_barrier()
#define LGKM0 asm volatile("s_waitcnt lgkmcnt(0)" ::: "memory")
#define LGKM8 asm volatile("s_waitcnt lgkmcnt(8)" ::: "memory")
#define VM6 asm volatile("s_waitcnt vmcnt(6)" ::: "memory")
#define PRIO1 __builtin_amdgcn_s_setprio(1)
#define PRIO0 __builtin_amdgcn_s_setprio(0)

  STG_B(0, 0, 0);
  STG_B(0, 1, 0);
  STG_A(0, 0, 0);
  STG_A(0, 1, 0);
  STG_B(1, 0, 1);
  STG_B(1, 1, 1);
  STG_A(1, 0, 1);
  VM6;
  BAR;

  bf16x8 Bf0[4], Bf1[4], Af0[4], Af1[4];

  for (int i = 0; i < (nt >> 1); ++i) {
    const int tb = 2 * i + 1;
    int t2 = 2 * i + 2; if (t2 >= nt) t2 -= nt;
    int t3 = 2 * i + 3; if (t3 >= nt) t3 -= nt;

    RD4(Bf0, bR);
    RD4(Bf1, bR ^ 32u);
    RD4(Af0, aR);
    STG_A(1, 1, tb);
    LGKM8;
    BAR; LGKM0;
    PRIO1; mm16<0>(acc, Af0, Bf0); PRIO0;
    BAR;
    RD4(Af1, aR + 4096u);
    STG_B(0, 0, t2);
    BAR; LGKM0;
    PRIO1; mm16<4>(acc, Af1, Bf0); PRIO0;
    BAR;
    RD4(Af0, aR ^ 32u);
    RD4(Af1, (aR + 4096u) ^ 32u);
    STG_B(0, 1, t2);
    BAR; LGKM0;
    PRIO1; mm16<0>(acc, Af0, Bf1); PRIO0;
    BAR;
    STG_A(0, 0, t2);
    VM6;
    BAR;
    PRIO1; mm16<4>(acc, Af1, Bf1); PRIO0;
    BAR;

    RD4(Bf0, 32768u + bR);
    RD4(Bf1, (32768u + bR) ^ 32u);
    RD4(Af0, 32768u + aR);
    STG_A(0, 1, t2);
    LGKM8;
    BAR; LGKM0;
    PRIO1; mm16<0>(acc, Af0, Bf0); PRIO0;
    BAR;
    RD4(Af1, 32768u + aR + 4096u);
    STG_B(1, 0, t3);
    BAR; LGKM0;
    PRIO1; mm16<4>(acc, Af1, Bf0); PRIO0;
    BAR;
    RD4(Af0, (32768u + aR) ^ 32u);
    RD4(Af1, (32768u + aR + 4096u) ^ 32u);
    STG_B(1, 1, t3);
    BAR; LGKM0;
    PRIO1; mm16<0>(acc, Af0, Bf1); PRIO0;
    BAR;
    STG_A(1, 0, t3);
    VM6;
    BAR;
    PRIO1; mm16<4>(acc, Af1, Bf1); PRIO0;
    BAR;
  }

  asm volatile("s_waitcnt vmcnt(0)" ::: "memory");

#undef STG_A
#undef STG_B
#undef RD4
#undef BAR
#undef LGKM0
#undef LGKM8
#undef VM6
#undef PRIO1
#undef PRIO0

  const int rb0 = m0 + wm * 128 + q * 4;
  const int cb0 = n0 + wn * 64 + c;
#pragma unroll
  for (int mf = 0; mf < 8; ++mf)
#pragma unroll
    for (int nf = 0; nf < 4; ++nf) {
      const size_t base = (size_t)(rb0 + mf * 16) * N + (cb0 + nf * 16);
#pragma unroll
      for (int r = 0; r < 4; ++r) {
        if (OUT_BF16)
          ((u16*)Cout)[base + (size_t)r * N] = f2bf(acc[mf][nf][r]);
        else
          ((float*)Cout)[base + (size_t)r * N] = acc[mf][nf][r];
      }
    }
}

// ---------------------------------------------------------------- qkv postprocess
__global__ __launch_bounds__(256) void qkv_post(const u16* __restrict__ raw,
                                                u16* __restrict__ qb,
                                                u16* __restrict__ kb) {
  const int t = threadIdx.x;
  const int c = t & 15, g = t >> 4;
  const u32 u = (u32)blockIdx.x * 16u + (u32)g;   // u < 163840
  const u32 row = u / 40u;
  const int hh = (int)(u - row * 40u);            // 0..39 (q:0-31, k:32-39)
  const int pos = (int)(row & 2047u);
  const int b = (int)(row >> 11);

  const uint4 rv = *(const uint4*)(raw + (size_t)row * 6144 + hh * 128 + c * 8);
  u32 rw[4] = {rv.x, rv.y, rv.z, rv.w};
  float xs[8];
#pragma unroll
  for (int j = 0; j < 4; ++j) {
    xs[2 * j] = bf2f((u16)(rw[j] & 0xffffu));
    xs[2 * j + 1] = bf2f((u16)(rw[j] >> 16));
  }
  float ss = 0.f;
#pragma unroll
  for (int j = 0; j < 8; ++j) ss += xs[j] * xs[j];
#pragma unroll
  for (int off = 8; off >= 1; off >>= 1) ss += __shfl_xor(ss, off);
  const float rn = rsqrtf(ss * (1.0f / 128.0f) + 1e-6f);

  u32 pw[4];
#pragma unroll
  for (int j = 0; j < 4; ++j) pw[j] = __shfl_xor(rw[j], 8);
  float xp[8];
#pragma unroll
  for (int j = 0; j < 4; ++j) {
    xp[2 * j] = bf2f((u16)(pw[j] & 0xffffu));
    xp[2 * j + 1] = bf2f((u16)(pw[j] >> 16));
  }

  const float sgn = (c < 8) ? -1.0f : 1.0f;
  const int dbase = (c & 7) * 8;
  const float fpos = (float)pos;
  const bool isq = (hh < 32);
  const float sc = (isq ? 0.088388347648318447f : 1.0f) * rn;
  float o[8];
#pragma unroll
  for (int j = 0; j < 8; ++j) {
    const float fr = exp2f(-(float)(dbase + j) * 0.20762050593046f);
    float sn, cs;
    sincosf(fpos * fr, &sn, &cs);
    o[j] = (xs[j] * cs + sgn * xp[j] * sn) * sc;
  }

  uint4 ov;
  ov.x = (u32)f2bf(o[0]) | ((u32)f2bf(o[1]) << 16);
  ov.y = (u32)f2bf(o[2]) | ((u32)f2bf(o[3]) << 16);
  ov.z = (u32)f2bf(o[4]) | ((u32)f2bf(o[5]) << 16);
  ov.w = (u32)f2bf(o[6]) | ((u32)f2bf(o[7]) << 16);
  u16* dst = isq ? (qb + ((size_t)((b * 32 + hh) * 2048 + pos)) * 128)
                 : (kb + ((size_t)((b * 8 + (hh - 32)) * 2048 + pos)) * 128);
  *(uint4*)(dst + c * 8) = ov;
}

// ---------------------------------------------------------------- flash attention
// R10: 32x32x16 MFMA structure. Block = (b,hq,64 queries); 4 waves.
// QK role (kh=w>>1, qh=w&1): S^T[key 32-strip][query 32-strip] = K*Q^T,
//   A=K from LDS (8KB/wave/tile, HALF of R9's 16KB), B=Q in regs.
// P (64x64, post-softcap-exp bf16) -> shared LDS, chunk^= (q&7) swizzle.
// PV role (dh=w>>1, qh=w&1): O[query strip][d 64-strip] += P*V,
//   A=P from LDS (4KB), B=V^T from LDS (8KB/wave/tile, half of R9).
// 3 barriers/tile. LDS: Ks 16K + VTs 16K + Ps 8K + Ls = 40.5KB -> 4 blk/CU.
// Layouts: C/D 32x32 (HW-verified m74/m101): col=lane&31,
//   row=(reg&3)+8*(reg>>2)+4*(lane>>5). A: row=lane&31, k=(lane>>5)*8+e;
//   B: col=lane&31, k=(lane>>5)*8+e (family pattern of the verified 16x16x32).
__global__ __launch_bounds__(256, 4) void attn_fwd(const u16* __restrict__ qb,
                                                   const u16* __restrict__ kb,
                                                   const u16* __restrict__ vtb,
                                                   u16* __restrict__ attn) {
  __shared__ __align__(16) u16 Ks[64 * 128];   // [key][d], slot^=(key&15)
  __shared__ __align__(16) u16 VTs[128 * 64];  // [d][key], slot^=(d&7)
  __shared__ __align__(16) u16 Ps[64 * 64];    // [q][key], slot^=(q&7)
  __shared__ float Ls[2][64];                  // per-kh lsum partials

  const int t = threadIdx.x, lane = t & 63, w = t >> 6;
  const int l31 = lane & 31, h5 = lane >> 5;
  const int kh = w >> 1, qh = w & 1;           // QK role; PV: dh = kh
  const int q0 = blockIdx.x * 64;
  const int bh = blockIdx.y;
  const int b = bh >> 5, hq = bh & 31;
  const int kvp = b * 8 + (hq >> 2);
  const u16* qp = qb + (size_t)bh * (2048 * 128);
  const u16* kp = kb + (size_t)kvp * (2048 * 128);
  const u16* vp = vtb + (size_t)kvp * (128 * 2048);

  // Q regs (B-frags): col q = qh*32+l31; qf[kst] holds d = kst*16 + h5*8 + e
  bf16x8 qf[8];
  {
    const u16* qrow = qp + (size_t)(q0 + qh * 32 + l31) * 128 + h5 * 8;
#pragma unroll
    for (int kst = 0; kst < 8; ++kst) qf[kst] = *(const bf16x8*)(qrow + kst * 16);
  }

  f32x16 oacc[2];
#pragma unroll
  for (int dc = 0; dc < 2; ++dc)
#pragma unroll
    for (int r = 0; r < 16; ++r) oacc[dc][r] = 0.0f;
  float lsum = 0.0f;

  const int iq = q0 + qh * 32 + l31;   // this lane's query (QK role)

  int t0 = q0 - 1023;
  if (t0 < 0) t0 = 0;
  t0 = (t0 >> 6) << 6;

  for (int kv0 = t0; kv0 <= q0; kv0 += 64) {
    __syncthreads();  // prev tile's PV reads retired (Ks/VTs/Ps WAR guard)
    {
      const int row_in = lane >> 4, ch = lane & 15;
#pragma unroll
      for (int i = 0; i < 4; ++i) {
        const int row = w * 4 + i * 16 + row_in;
        const int g = ch ^ (row & 15);
        load_lds16(kp + (size_t)(kv0 + row) * 128 + g * 8, &Ks[(w * 4 + i * 16) * 128]);
      }
      const int drow = lane >> 3, ch8 = lane & 7;
#pragma unroll
      for (int i = 0; i < 4; ++i) {
        const int dd = w * 8 + i * 32 + drow;
        const int g = ch8 ^ (dd & 7);
        load_lds16(vp + (size_t)dd * 2048 + kv0 + g * 8, &VTs[(w * 8 + i * 32) * 64]);
      }
    }
    __syncthreads();  // staging complete

    // ---- S^T[key][q]: wave (kh,qh) computes 32 keys x 32 queries
    f32x16 sacc;
#pragma unroll
    for (int r = 0; r < 16; ++r) sacc[r] = 0.0f;
    {
      const int key = kh * 32 + l31;
      const u16* krow = &Ks[key * 128];
      const int s15 = key & 15;
#pragma unroll
      for (int kst = 0; kst < 8; ++kst) {
        const int phys = (kst * 2 + h5) ^ s15;
        const bf16x8 af = *(const bf16x8*)(krow + phys * 8);
        sacc = __builtin_amdgcn_mfma_f32_32x32x16_bf16(af, qf[kst], sacc, 0, 0, 0);
      }
    }

    // ---- softcap + exp (fixed max); mask only boundary tiles
    const bool need_mask = (kv0 == q0) || (q0 - kv0 >= 961);
    float pv[16];
#pragma unroll
    for (int r = 0; r < 16; ++r) {
      const float s = sacc[r];
      const float u = s * s;
      // 50*tanh(s/50) = s*(1 - u/7500 + 2u^2/9.375e7), |s|<=11.4
      const float cap = s * (1.0f + u * (-1.3333333e-4f + u * 2.1333333e-8f));
      pv[r] = __expf(cap);
    }
    if (need_mask) {
#pragma unroll
      for (int r = 0; r < 16; ++r) {
        const int key = kv0 + kh * 32 + (r & 3) + 8 * (r >> 2) + 4 * h5;
        if (!((key <= iq) && (iq - key < 1024))) pv[r] = 0.0f;
      }
    }
#pragma unroll
    for (int r = 0; r < 16; ++r) lsum += pv[r];

    // ---- P -> LDS: row q = qh*32+l31; keys kh*32 + 8g + 4h5 + {0..3}
    {
      const int qrow = qh * 32 + l31;
      u16* prow = &Ps[qrow * 64];
      const int s7 = l31 & 7;
#pragma unroll
      for (int g = 0; g < 4; ++g) {
        uint2 pk;
        pk.x = pack_trunc(pv[4 * g + 0], pv[4 * g + 1]);
        pk.y = pack_trunc(pv[4 * g + 2], pv[4 * g + 3]);
        const int phys = (kh * 4 + g) ^ s7;
        *(uint2*)(prow + phys * 8 + h5 * 4) = pk;
      }
    }
    __syncthreads();  // P visible to all waves

    // ---- PV: wave (dh=kh, qh): O[32q][64d] += P[32q][64k] * V[64k][64d]
    {
      const u16* prow = &Ps[(qh * 32 + l31) * 64];
      const int s7 = l31 & 7;
#pragma unroll
      for (int kst = 0; kst < 4; ++kst) {
        const int physp = (kst * 2 + h5) ^ s7;
        const bf16x8 pf = *(const bf16x8*)(prow + physp * 8);
#pragma unroll
        for (int dc = 0; dc < 2; ++dc) {
          const int drow = kh * 64 + dc * 32 + l31;
          const int physv = (kst * 2 + h5) ^ (drow & 7);
          const bf16x8 vf = *(const bf16x8*)&VTs[drow * 64 + physv * 8];
          oacc[dc] = __builtin_amdgcn_mfma_f32_32x32x16_bf16(pf, vf, oacc[dc], 0, 0, 0);
        }
      }
    }
  }

  // ---- cross-wave lsum combine + normalize + store
  float lt = lsum + __shfl_xor(lsum, 32);
  if (lane < 32) Ls[kh][qh * 32 + lane] = lt;
  __syncthreads();

  float rl16[16];
#pragma unroll
  for (int r = 0; r < 16; ++r) {
    const int qi = qh * 32 + (r & 3) + 8 * (r >> 2) + 4 * h5;
    rl16[r] = __builtin_amdgcn_rcpf(Ls[0][qi] + Ls[1][qi]);
  }

  const size_t ob = ((size_t)(b * 2048 + q0 + qh * 32)) * 4096 + hq * 128 + kh * 64;
#pragma unroll
  for (int dc = 0; dc < 2; ++dc)
#pragma unroll
    for (int r = 0; r < 16; ++r) {
      const int qi = (r & 3) + 8 * (r >> 2) + 4 * h5;
      attn[ob + (size_t)qi * 4096 + dc * 32 + l31] = f2bf(oacc[dc][r] * rl16[r]);
    }
}

// ---------------------------------------------------------------- launch
extern "C" void kernel_launch(void* const* d_in, const int* in_sizes, int n_in,
                              void* d_out, int out_size, void* d_ws, size_t ws_size,
                              hipStream_t stream) {
  (void)in_sizes; (void)n_in; (void)out_size; (void)ws_size;
  const float* x  = (const float*)d_in[0];
  const float* Wq = (const float*)d_in[1];
  const float* Wk = (const float*)d_in[2];
  const float* Wv = (const float*)d_in[3];
  const float* Wo = (const float*)d_in[4];
  float* out = (float*)d_out;
  char* ws = (char*)d_ws;

  u16* xb    = (u16*)(ws + 0);
  u16* vtb   = (u16*)(ws + 0);
  u16* WqkvT = (u16*)(ws + 33554432ULL);
  u16* qb    = (u16*)(ws + 33554432ULL);
  u16* kb    = (u16*)(ws + 67108864ULL);
  u16* WoT   = (u16*)(ws + 83886080ULL);
  u16* qkvr  = (u16*)(ws + 117440512ULL);
  u16* attnb = (u16*)(ws + 117440512ULL);

  cast_f32_bf16<<<8192, 256, 0, stream>>>(x, xb);
  transpose_cast_f32_bf16<<<dim3(128, 128), 256, 0, stream>>>(Wq, WqkvT, 4096, 4096);
  transpose_cast_f32_bf16<<<dim3(32, 128), 256, 0, stream>>>(Wk, WqkvT + (size_t)4096 * 4096, 4096, 1024);
  transpose_cast_f32_bf16<<<dim3(32, 128), 256, 0, stream>>>(Wv, WqkvT + (size_t)5120 * 4096, 4096, 1024);
  transpose_cast_f32_bf16<<<dim3(128, 128), 256, 0, stream>>>(Wo, WoT, 4096, 4096);

  // QKV: M=4096, N=6144, K=4096 -> 16x24 = 384 tiles (384 % 8 == 0)
  gemm256<1><<<dim3(384), 512, 0, stream>>>(xb, WqkvT, (void*)qkvr, 6144, 4096, 24);
  qkv_post<<<10240, 256, 0, stream>>>(qkvr, qb, kb);
  transpose_v<<<dim3(64, 4, 16), 256, 0, stream>>>(qkvr, vtb);
  attn_fwd<<<dim3(32, 64), 256, 0, stream>>>(qb, kb, vtb, attnb);
  // Out: M=4096, N=4096, K=4096 -> 16x16 = 256 tiles (256 % 8 == 0)
  gemm256<0><<<dim3(256), 512, 0, stream>>>(attnb, WoT, (void*)out, 4096, 4096, 16);
}